// Round 1
// baseline (505.395 us; speedup 1.0000x reference)
//
#include <hip/hip_runtime.h>

#define NROWS 65536
#define DDIM  512
#define NCLS  64

// ws layout (floats): [0,32768) sums[64][512] ; [32768,32832) counts[64] ;
//                     [32832,65600) cent[64][512] (pre-scaled by 1/(count*TEMP))
static constexpr int WS_SUMS   = 0;
static constexpr int WS_COUNTS = 32768;
static constexpr int WS_CENT   = 32832;
static constexpr float SCALE = 0.25f / (float)NROWS;  // (1-GLW)/2 = GLW/2 = 0.25, / N

__global__ __launch_bounds__(256) void k_counts(const int* __restrict__ seg,
                                                float* __restrict__ counts) {
  __shared__ int c[NCLS];
  const int t = threadIdx.x;
  if (t < NCLS) c[t] = 0;
  __syncthreads();
  for (int i = blockIdx.x * 256 + t; i < NROWS; i += gridDim.x * 256)
    atomicAdd(&c[seg[i]], 1);
  __syncthreads();
  if (t < NCLS) atomicAdd(&counts[t], (float)c[t]);
}

// 512 blocks: cg = blockIdx&7 (64-col slab), rg = blockIdx>>3 (1024-row slab).
// LDS acc[64 classes][64 cols] (+1 pad) accumulated with LDS atomics.
__global__ __launch_bounds__(256) void k_sums(const float* __restrict__ S1,
                                              const int* __restrict__ seg,
                                              float* __restrict__ sums) {
  __shared__ float acc[NCLS][65];
  const int t = threadIdx.x;
  for (int idx = t; idx < NCLS * 65; idx += 256) (&acc[0][0])[idx] = 0.f;
  __syncthreads();
  const int cg   = blockIdx.x & 7;
  const int rg   = blockIdx.x >> 3;
  const int col0 = cg * 64;
  const int row0 = rg * 1024;
  const int cq   = t & 15;   // float4 quad within the 64-col slab
  const int rof  = t >> 4;   // 16 rows in flight per iteration
  for (int r = row0 + rof; r < row0 + 1024; r += 16) {
    const int lab = seg[r];
    const float4 v = *(const float4*)&S1[(size_t)r * DDIM + col0 + cq * 4];
    atomicAdd(&acc[lab][cq * 4 + 0], v.x);
    atomicAdd(&acc[lab][cq * 4 + 1], v.y);
    atomicAdd(&acc[lab][cq * 4 + 2], v.z);
    atomicAdd(&acc[lab][cq * 4 + 3], v.w);
  }
  __syncthreads();
  for (int idx = t; idx < NCLS * 64; idx += 256) {
    const int c = idx >> 6, d = idx & 63;
    atomicAdd(&sums[c * DDIM + col0 + d], acc[c][d]);
  }
}

__global__ __launch_bounds__(256) void k_cent(const float* __restrict__ sums,
                                              const float* __restrict__ counts,
                                              float* __restrict__ cent) {
  const int idx = blockIdx.x * 256 + threadIdx.x;   // 32768 total
  const int c = idx >> 9;
  cent[idx] = sums[idx] * (10.0f / counts[c]);      // fold 1/TEMP = 10
}

// 2048 blocks; block b owns 64 consecutive rows of the virtual 2N-row stream
// (first 1024 blocks: S1 rows, rest: S2 rows). 64x64 logits per block via
// fp32 FMA GEMM tiling (Dk=32, 4x4 per-thread tile), then fused CE epilogue.
__global__ __launch_bounds__(256) void k_loss(const float* __restrict__ S1,
                                              const float* __restrict__ S2,
                                              const int* __restrict__ seg,
                                              const float* __restrict__ sim,
                                              const float* __restrict__ cent,
                                              float* __restrict__ out) {
  __shared__ __align__(16) float lds[2 * 32 * 68];  // St | Ct, reused as Lg[64][68]
  float* St = lds;
  float* Ct = lds + 32 * 68;
  const int t = threadIdx.x;
  const int g0 = blockIdx.x * 64;            // base row in [0, 2N)
  const bool isS2 = (g0 >= NROWS);
  const float* S = isS2 ? S2 : S1;
  const int i0 = isS2 ? (g0 - NROWS) : g0;   // row base within the matrix

  const int tr = t & 15;   // 4-row group
  const int tc = t >> 4;   // 4-class group
  const int kk = t & 31;   // staging: k within chunk
  const int rr = t >> 5;   // staging: 8 rows/classes per pass

  float acc[4][4] = {};
  for (int d0 = 0; d0 < DDIM; d0 += 32) {
    __syncthreads();
#pragma unroll
    for (int p = 0; p < 8; ++p) {
      const int row = rr * 8 + p;
      St[kk * 68 + row] = S[(size_t)(i0 + row) * DDIM + d0 + kk];
      Ct[kk * 68 + row] = cent[(size_t)row * DDIM + d0 + kk];  // row == class
    }
    __syncthreads();
#pragma unroll 8
    for (int k = 0; k < 32; ++k) {
      const float4 a4 = *(const float4*)&St[k * 68 + tr * 4];
      const float4 b4 = *(const float4*)&Ct[k * 68 + tc * 4];
      const float av[4] = {a4.x, a4.y, a4.z, a4.w};
      const float bv[4] = {b4.x, b4.y, b4.z, b4.w};
#pragma unroll
      for (int r = 0; r < 4; ++r)
#pragma unroll
        for (int c = 0; c < 4; ++c)
          acc[r][c] = fmaf(av[r], bv[c], acc[r][c]);
    }
  }

  // dump logits (already /TEMP via cent scaling) to LDS: Lg[row][cls], stride 68
  __syncthreads();
  float* Lg = lds;
#pragma unroll
  for (int r = 0; r < 4; ++r) {
    float4 v;
    v.x = acc[r][0]; v.y = acc[r][1]; v.z = acc[r][2]; v.w = acc[r][3];
    *(float4*)&Lg[(tr * 4 + r) * 68 + tc * 4] = v;
  }
  __syncthreads();

  if (t < 64) {  // one wave: one row per lane
    const int r = t;
    float mx = -1e30f;
#pragma unroll
    for (int c4 = 0; c4 < 16; ++c4) {
      const float4 v = *(const float4*)&Lg[r * 68 + c4 * 4];
      mx = fmaxf(mx, fmaxf(fmaxf(v.x, v.y), fmaxf(v.z, v.w)));
    }
    float sum = 0.f;
#pragma unroll
    for (int c4 = 0; c4 < 16; ++c4) {
      const float4 v = *(const float4*)&Lg[r * 68 + c4 * 4];
      sum += __expf(v.x - mx) + __expf(v.y - mx) + __expf(v.z - mx) + __expf(v.w - mx);
    }
    const int lab = seg[i0 + r];
    const float ce = mx + __logf(sum) - Lg[r * 68 + lab];
    const float4* sp = (const float4*)&sim[(size_t)(i0 + r) * 16];
    const float4 w0 = sp[0], w1 = sp[1], w2 = sp[2], w3 = sp[3];
    const float w = (w0.x + w0.y + w0.z + w0.w + w1.x + w1.y + w1.z + w1.w +
                     w2.x + w2.y + w2.z + w2.w + w3.x + w3.y + w3.z + w3.w) * (1.0f / 16.0f);
    float v = ce * w * SCALE;
#pragma unroll
    for (int off = 32; off > 0; off >>= 1) v += __shfl_down(v, off, 64);
    if (t == 0) atomicAdd(out, v);
  }
}

extern "C" void kernel_launch(void* const* d_in, const int* in_sizes, int n_in,
                              void* d_out, int out_size, void* d_ws, size_t ws_size,
                              hipStream_t stream) {
  const float* S1  = (const float*)d_in[0];
  const float* S2  = (const float*)d_in[1];
  const int*   seg = (const int*)d_in[2];
  const float* sim = (const float*)d_in[3];
  float* ws     = (float*)d_ws;
  float* sums   = ws + WS_SUMS;
  float* counts = ws + WS_COUNTS;
  float* cent   = ws + WS_CENT;
  float* out    = (float*)d_out;

  hipMemsetAsync(d_ws, 0, (size_t)(32768 + 64) * sizeof(float), stream);
  hipMemsetAsync(d_out, 0, sizeof(float), stream);

  k_counts<<<64,   256, 0, stream>>>(seg, counts);
  k_sums<<<512,   256, 0, stream>>>(S1, seg, sums);
  k_cent<<<128,   256, 0, stream>>>(sums, counts, cent);
  k_loss<<<2048,  256, 0, stream>>>(S1, S2, seg, sim, cent, out);
}

// Round 2
// 442.346 us; speedup vs baseline: 1.1425x; 1.1425x over previous
//
#include <hip/hip_runtime.h>

#define NROWS 65536
#define DDIM  512
#define NCLS  64

typedef __attribute__((ext_vector_type(4))) float  floatx4;
typedef __attribute__((ext_vector_type(8))) short  shortx8;
typedef __attribute__((ext_vector_type(4))) short  shortx4;

static constexpr float SCALE = 0.25f / (float)NROWS;  // (1-GLW)/2 = GLW/2 = 0.25, / N

// ws byte offsets
static constexpr size_t OFF_SUMS    = 0;        // f32 [64][512] = 131072 B
static constexpr size_t OFF_HIST    = 131072;   // int [64]
static constexpr size_t OFF_CURSOR  = 131328;   // int [64]
static constexpr size_t OFF_STARTS  = 131584;   // int [65]
static constexpr size_t OFF_COUNTSF = 132096;   // f32 [64]
static constexpr size_t OFF_IDX     = 132352;   // int [65536] = 262144 B
static constexpr size_t OFF_CENTBF  = 394496;   // bf16 [64][512] = 65536 B
// total ~460 KB

__device__ __forceinline__ unsigned short f2bf(float f) {  // round-to-nearest-even
  unsigned u = __float_as_uint(f);
  return (unsigned short)((u + 0x7fffu + ((u >> 16) & 1u)) >> 16);
}

__global__ __launch_bounds__(256) void k_hist(const int* __restrict__ seg,
                                              int* __restrict__ hist) {
  __shared__ int h[NCLS];
  const int t = threadIdx.x;
  if (t < NCLS) h[t] = 0;
  __syncthreads();
  atomicAdd(&h[seg[blockIdx.x * 256 + t]], 1);
  __syncthreads();
  if (t < NCLS) atomicAdd(&hist[t], h[t]);
}

__global__ void k_scan(const int* __restrict__ hist, int* __restrict__ starts,
                       float* __restrict__ countsf) {
  __shared__ int h[NCLS];
  const int t = threadIdx.x;  // 64 threads
  h[t] = hist[t];
  __syncthreads();
  int s = 0;
  for (int i = 0; i < t; ++i) s += h[i];
  starts[t] = s;
  if (t == 63) starts[64] = s + h[63];
  countsf[t] = (float)h[t];
}

__global__ __launch_bounds__(256) void k_scatter(const int* __restrict__ seg,
                                                 const int* __restrict__ starts,
                                                 int* __restrict__ cursor,
                                                 int* __restrict__ idx) {
  const int i = blockIdx.x * 256 + threadIdx.x;
  const int lab = seg[i];
  const int pos = atomicAdd(&cursor[lab], 1);
  idx[starts[lab] + pos] = i;
}

// 512 blocks = 64 classes x 8 col-eighths. 256 threads = 4 row-substreams x 64 cols.
// Register accumulation over the class's (sorted-contiguous) row list. No LDS.
__global__ __launch_bounds__(256) void k_sumsC(const float* __restrict__ S1,
                                               const int* __restrict__ idx,
                                               const int* __restrict__ starts,
                                               float* __restrict__ sums) {
  const int c  = blockIdx.x >> 3;
  const int qq = blockIdx.x & 7;
  const int t  = threadIdx.x;
  const int sub = t >> 6;
  const int col = qq * 64 + (t & 63);
  const int s0 = starts[c];
  const int n  = starts[c + 1] - s0;
  const int n4 = n >> 2;
  const int base = s0 + sub * n4;
  const int len  = (sub == 3) ? (n - 3 * n4) : n4;
  const float* Sc = S1 + col;
  float a0 = 0.f, a1 = 0.f, a2 = 0.f, a3 = 0.f;
  int j = 0;
  for (; j + 8 <= len; j += 8) {
    const int* ip = idx + base + j;
    const int r0 = ip[0], r1 = ip[1], r2 = ip[2], r3 = ip[3];
    const int r4 = ip[4], r5 = ip[5], r6 = ip[6], r7 = ip[7];
    a0 += Sc[(size_t)r0 * DDIM]; a1 += Sc[(size_t)r1 * DDIM];
    a2 += Sc[(size_t)r2 * DDIM]; a3 += Sc[(size_t)r3 * DDIM];
    a0 += Sc[(size_t)r4 * DDIM]; a1 += Sc[(size_t)r5 * DDIM];
    a2 += Sc[(size_t)r6 * DDIM]; a3 += Sc[(size_t)r7 * DDIM];
  }
  for (; j < len; ++j) a0 += Sc[(size_t)idx[base + j] * DDIM];
  atomicAdd(&sums[(size_t)c * DDIM + col], a0 + a1 + a2 + a3);
}

__global__ __launch_bounds__(256) void k_cent(const float* __restrict__ sums,
                                              const float* __restrict__ countsf,
                                              unsigned short* __restrict__ centbf) {
  const int i = blockIdx.x * 256 + threadIdx.x;  // 32768, grid 128
  const int c = i >> 9;
  centbf[i] = f2bf(sums[i] * (10.0f / countsf[c]));  // fold 1/TEMP = 10
}

// 2048 blocks; block owns 64 rows of the virtual 2N stream x all 64 classes.
// bf16 MFMA 16x16x32, BK=64, LDS tiles stride 72 bf16 (=144 B = 9x16 B -> even b128 spread).
__global__ __launch_bounds__(256) void k_loss(const float* __restrict__ S1,
                                              const float* __restrict__ S2,
                                              const int* __restrict__ seg,
                                              const float* __restrict__ sim,
                                              const unsigned short* __restrict__ centbf,
                                              float* __restrict__ out) {
  __shared__ __align__(16) char smem[18432];
  short* Sa = (short*)smem;            // [64][72] bf16
  short* Cb = (short*)(smem + 9216);   // [64][72] bf16
  float* Lg = (float*)smem;            // [64][68] f32 (epilogue, aliases tiles)

  const int t = threadIdx.x;
  const int g0 = blockIdx.x * 64;
  const bool isS2 = (g0 >= NROWS);
  const float* S = isS2 ? S2 : S1;
  const int i0 = isS2 ? (g0 - NROWS) : g0;

  const int lane = t & 63;
  const int w    = t >> 6;       // wave id: rows [w*16, w*16+16)
  const int m    = lane & 15;
  const int quad = lane >> 4;

  floatx4 acc0 = {0.f,0.f,0.f,0.f}, acc1 = {0.f,0.f,0.f,0.f};
  floatx4 acc2 = {0.f,0.f,0.f,0.f}, acc3 = {0.f,0.f,0.f,0.f};

  const int srow = t >> 2;       // staging row/class
  const int sfq  = t & 3;

  for (int d0 = 0; d0 < DDIM; d0 += 64) {
    __syncthreads();
    {
      // stage S tile: 64 rows x 64 k (fp32 -> bf16)
      const float* src = &S[(size_t)(i0 + srow) * DDIM + d0];
#pragma unroll
      for (int p = 0; p < 4; ++p) {
        const int col = p * 16 + sfq * 4;
        const float4 v = *(const float4*)&src[col];
        shortx4 b;
        b.x = (short)f2bf(v.x); b.y = (short)f2bf(v.y);
        b.z = (short)f2bf(v.z); b.w = (short)f2bf(v.w);
        *(shortx4*)&Sa[srow * 72 + col] = b;
      }
      // stage centroid tile: 64 cls x 64 k (already bf16)
      const int e0 = sfq * 16;
      const short* cs = (const short*)&centbf[(size_t)srow * DDIM + d0 + e0];
      *(shortx8*)&Cb[srow * 72 + e0]     = *(const shortx8*)cs;
      *(shortx8*)&Cb[srow * 72 + e0 + 8] = *(const shortx8*)(cs + 8);
    }
    __syncthreads();
#pragma unroll
    for (int kk = 0; kk < 64; kk += 32) {
      const shortx8 a = *(const shortx8*)&Sa[(w * 16 + m) * 72 + kk + quad * 8];
      const shortx8 b0 = *(const shortx8*)&Cb[(0  + m) * 72 + kk + quad * 8];
      acc0 = __builtin_amdgcn_mfma_f32_16x16x32_bf16(a, b0, acc0, 0, 0, 0);
      const shortx8 b1 = *(const shortx8*)&Cb[(16 + m) * 72 + kk + quad * 8];
      acc1 = __builtin_amdgcn_mfma_f32_16x16x32_bf16(a, b1, acc1, 0, 0, 0);
      const shortx8 b2 = *(const shortx8*)&Cb[(32 + m) * 72 + kk + quad * 8];
      acc2 = __builtin_amdgcn_mfma_f32_16x16x32_bf16(a, b2, acc2, 0, 0, 0);
      const shortx8 b3 = *(const shortx8*)&Cb[(48 + m) * 72 + kk + quad * 8];
      acc3 = __builtin_amdgcn_mfma_f32_16x16x32_bf16(a, b3, acc3, 0, 0, 0);
    }
  }

  // dump logits to LDS: Lg[row][cls], stride 68. D layout: col=lane&15, row=quad*4+reg
  __syncthreads();
#pragma unroll
  for (int r = 0; r < 4; ++r) {
    const int row = w * 16 + quad * 4 + r;
    Lg[row * 68 + 0  + m] = acc0[r];
    Lg[row * 68 + 16 + m] = acc1[r];
    Lg[row * 68 + 32 + m] = acc2[r];
    Lg[row * 68 + 48 + m] = acc3[r];
  }
  __syncthreads();

  if (t < 64) {  // one wave: one row per lane; logits already include 1/TEMP
    const int r = t;
    float mx = -1e30f;
#pragma unroll
    for (int c4 = 0; c4 < 16; ++c4) {
      const float4 v = *(const float4*)&Lg[r * 68 + c4 * 4];
      mx = fmaxf(mx, fmaxf(fmaxf(v.x, v.y), fmaxf(v.z, v.w)));
    }
    float sum = 0.f;
#pragma unroll
    for (int c4 = 0; c4 < 16; ++c4) {
      const float4 v = *(const float4*)&Lg[r * 68 + c4 * 4];
      sum += __expf(v.x - mx) + __expf(v.y - mx) + __expf(v.z - mx) + __expf(v.w - mx);
    }
    const int lab = seg[i0 + r];
    const float ce = mx + __logf(sum) - Lg[r * 68 + lab];
    const float4* sp = (const float4*)&sim[(size_t)(i0 + r) * 16];
    const float4 w0 = sp[0], w1 = sp[1], w2 = sp[2], w3 = sp[3];
    const float wgt = (w0.x + w0.y + w0.z + w0.w + w1.x + w1.y + w1.z + w1.w +
                       w2.x + w2.y + w2.z + w2.w + w3.x + w3.y + w3.z + w3.w) * (1.0f / 16.0f);
    float v = ce * wgt * SCALE;
#pragma unroll
    for (int off = 32; off > 0; off >>= 1) v += __shfl_down(v, off, 64);
    if (t == 0) atomicAdd(out, v);
  }
}

extern "C" void kernel_launch(void* const* d_in, const int* in_sizes, int n_in,
                              void* d_out, int out_size, void* d_ws, size_t ws_size,
                              hipStream_t stream) {
  const float* S1  = (const float*)d_in[0];
  const float* S2  = (const float*)d_in[1];
  const int*   seg = (const int*)d_in[2];
  const float* sim = (const float*)d_in[3];
  char* ws = (char*)d_ws;
  float* sums    = (float*)(ws + OFF_SUMS);
  int*   hist    = (int*)(ws + OFF_HIST);
  int*   cursor  = (int*)(ws + OFF_CURSOR);
  int*   starts  = (int*)(ws + OFF_STARTS);
  float* countsf = (float*)(ws + OFF_COUNTSF);
  int*   idx     = (int*)(ws + OFF_IDX);
  unsigned short* centbf = (unsigned short*)(ws + OFF_CENTBF);
  float* out = (float*)d_out;

  hipMemsetAsync(d_ws, 0, OFF_STARTS, stream);   // sums + hist + cursor
  hipMemsetAsync(d_out, 0, sizeof(float), stream);

  k_hist<<<256, 256, 0, stream>>>(seg, hist);
  k_scan<<<1, 64, 0, stream>>>(hist, starts, countsf);
  k_scatter<<<256, 256, 0, stream>>>(seg, starts, cursor, idx);
  k_sumsC<<<512, 256, 0, stream>>>(S1, idx, starts, sums);
  k_cent<<<128, 256, 0, stream>>>(sums, countsf, centbf);
  k_loss<<<2048, 256, 0, stream>>>(S1, S2, seg, sim, centbf, out);
}

// Round 3
// 335.681 us; speedup vs baseline: 1.5056x; 1.3178x over previous
//
#include <hip/hip_runtime.h>

#define NROWS 65536
#define DDIM  512
#define NCLS  64

typedef __attribute__((ext_vector_type(4))) float  floatx4;
typedef __attribute__((ext_vector_type(8))) short  shortx8;
typedef __attribute__((ext_vector_type(4))) short  shortx4;

static constexpr float SCALE = 0.25f / (float)NROWS;  // (1-GLW)/2 = GLW/2 = 0.25, / N

// ws byte offsets
static constexpr size_t OFF_SUMS   = 0;        // f32 [64][512] = 131072 B (plain stores, no memset)
static constexpr size_t OFF_HIST   = 131072;   // int [64]
static constexpr size_t OFF_CURSOR = 131328;   // int [64]
static constexpr size_t OFF_IDX    = 131584;   // int [65536] = 262144 B
static constexpr size_t OFF_CENTBF = 393728;   // bf16 [64][512] = 65536 B

__device__ __forceinline__ unsigned short f2bf(float f) {  // round-to-nearest-even
  unsigned u = __float_as_uint(f);
  return (unsigned short)((u + 0x7fffu + ((u >> 16) & 1u)) >> 16);
}

// 64 blocks x 256 threads x 4 rows (int4)
__global__ __launch_bounds__(256) void k_hist(const int* __restrict__ seg,
                                              int* __restrict__ hist) {
  __shared__ int h[NCLS];
  const int t = threadIdx.x;
  if (t < NCLS) h[t] = 0;
  __syncthreads();
  const int4 v = ((const int4*)seg)[blockIdx.x * 256 + t];
  atomicAdd(&h[v.x], 1); atomicAdd(&h[v.y], 1);
  atomicAdd(&h[v.z], 1); atomicAdd(&h[v.w], 1);
  __syncthreads();
  if (t < NCLS) atomicAdd(&hist[t], h[t]);
}

// 32 blocks x 1024 threads x 2 rows. Rank via LDS atomic (returns old),
// base via per-class block reservation (32 contended atomics/address total).
// Global starts recomputed per block from hist via wave shfl-scan.
__global__ __launch_bounds__(1024) void k_scatter2(const int* __restrict__ seg,
                                                   const int* __restrict__ hist,
                                                   int* __restrict__ cursor,
                                                   int* __restrict__ idx) {
  __shared__ int lhist[NCLS];
  __shared__ int gbase[NCLS];
  const int t = threadIdx.x;
  if (t < NCLS) lhist[t] = 0;
  __syncthreads();
  const int i0 = blockIdx.x * 2048 + t;
  const int lab0 = seg[i0];
  const int r0 = atomicAdd(&lhist[lab0], 1);
  const int i1 = i0 + 1024;
  const int lab1 = seg[i1];
  const int r1 = atomicAdd(&lhist[lab1], 1);
  __syncthreads();
  if (t < NCLS) {
    const int h = hist[t];
    int x = h;
#pragma unroll
    for (int off = 1; off < 64; off <<= 1) {
      const int y = __shfl_up(x, off, 64);
      if (t >= off) x += y;
    }
    gbase[t] = (x - h) + atomicAdd(&cursor[t], lhist[t]);
  }
  __syncthreads();
  idx[gbase[lab0] + r0] = i0;
  idx[gbase[lab1] + r1] = i1;
}

// 512 blocks = 64 classes x 8 col-eighths. 256 threads = 4 row-substreams x 64 cols.
// Register accumulation over the class's contiguous row list; LDS reduce; plain store.
__global__ __launch_bounds__(256) void k_sumsC(const float* __restrict__ S1,
                                               const int* __restrict__ idx,
                                               const int* __restrict__ hist,
                                               float* __restrict__ sums) {
  __shared__ int sh_start[NCLS + 1];
  __shared__ float red[256];
  const int c  = blockIdx.x >> 3;
  const int qq = blockIdx.x & 7;
  const int t  = threadIdx.x;
  if (t < 64) {
    const int h = hist[t];
    int x = h;
#pragma unroll
    for (int off = 1; off < 64; off <<= 1) {
      const int y = __shfl_up(x, off, 64);
      if (t >= off) x += y;
    }
    sh_start[t] = x - h;
    if (t == 63) sh_start[64] = x;
  }
  __syncthreads();
  const int s0 = sh_start[c];
  const int n  = sh_start[c + 1] - s0;
  const int sub = t >> 6;
  const int col = qq * 64 + (t & 63);
  const int n4 = n >> 2;
  const int base = s0 + sub * n4;
  const int len  = (sub == 3) ? (n - 3 * n4) : n4;
  const float* Sc = S1 + col;
  float a0 = 0.f, a1 = 0.f, a2 = 0.f, a3 = 0.f;
  int j = 0;
  for (; j + 8 <= len; j += 8) {
    const int* ip = idx + base + j;
    const int r0 = ip[0], r1 = ip[1], r2 = ip[2], r3 = ip[3];
    const int r4 = ip[4], r5 = ip[5], r6 = ip[6], r7 = ip[7];
    a0 += Sc[(size_t)r0 * DDIM]; a1 += Sc[(size_t)r1 * DDIM];
    a2 += Sc[(size_t)r2 * DDIM]; a3 += Sc[(size_t)r3 * DDIM];
    a0 += Sc[(size_t)r4 * DDIM]; a1 += Sc[(size_t)r5 * DDIM];
    a2 += Sc[(size_t)r6 * DDIM]; a3 += Sc[(size_t)r7 * DDIM];
  }
  for (; j < len; ++j) a0 += Sc[(size_t)idx[base + j] * DDIM];
  red[t] = a0 + a1 + a2 + a3;
  __syncthreads();
  if (t < 64)
    sums[(size_t)c * DDIM + col] = red[t] + red[t + 64] + red[t + 128] + red[t + 192];
}

__global__ __launch_bounds__(256) void k_cent(const float* __restrict__ sums,
                                              const int* __restrict__ hist,
                                              unsigned short* __restrict__ centbf) {
  const int i = blockIdx.x * 256 + threadIdx.x;  // grid 128
  const int c = i >> 9;
  centbf[i] = f2bf(sums[i] * (10.0f / (float)hist[c]));  // fold 1/TEMP = 10
}

// 2048 blocks; block owns 64 rows of the virtual 2N stream x all 64 classes.
// bf16 MFMA 16x16x32, BK=64, LDS tiles stride 72 bf16.
__global__ __launch_bounds__(256) void k_loss(const float* __restrict__ S1,
                                              const float* __restrict__ S2,
                                              const int* __restrict__ seg,
                                              const float* __restrict__ sim,
                                              const unsigned short* __restrict__ centbf,
                                              float* __restrict__ out) {
  __shared__ __align__(16) char smem[18432];
  short* Sa = (short*)smem;            // [64][72] bf16
  short* Cb = (short*)(smem + 9216);   // [64][72] bf16
  float* Lg = (float*)smem;            // [64][68] f32 (epilogue, aliases tiles)

  const int t = threadIdx.x;
  const int g0 = blockIdx.x * 64;
  const bool isS2 = (g0 >= NROWS);
  const float* S = isS2 ? S2 : S1;
  const int i0 = isS2 ? (g0 - NROWS) : g0;

  const int lane = t & 63;
  const int w    = t >> 6;
  const int m    = lane & 15;
  const int quad = lane >> 4;

  floatx4 acc0 = {0.f,0.f,0.f,0.f}, acc1 = {0.f,0.f,0.f,0.f};
  floatx4 acc2 = {0.f,0.f,0.f,0.f}, acc3 = {0.f,0.f,0.f,0.f};

  const int srow = t >> 2;
  const int sfq  = t & 3;

  for (int d0 = 0; d0 < DDIM; d0 += 64) {
    __syncthreads();
    {
      const float* src = &S[(size_t)(i0 + srow) * DDIM + d0];
#pragma unroll
      for (int p = 0; p < 4; ++p) {
        const int col = p * 16 + sfq * 4;
        const float4 v = *(const float4*)&src[col];
        shortx4 b;
        b.x = (short)f2bf(v.x); b.y = (short)f2bf(v.y);
        b.z = (short)f2bf(v.z); b.w = (short)f2bf(v.w);
        *(shortx4*)&Sa[srow * 72 + col] = b;
      }
      const int e0 = sfq * 16;
      const short* cs = (const short*)&centbf[(size_t)srow * DDIM + d0 + e0];
      *(shortx8*)&Cb[srow * 72 + e0]     = *(const shortx8*)cs;
      *(shortx8*)&Cb[srow * 72 + e0 + 8] = *(const shortx8*)(cs + 8);
    }
    __syncthreads();
#pragma unroll
    for (int kk = 0; kk < 64; kk += 32) {
      const shortx8 a = *(const shortx8*)&Sa[(w * 16 + m) * 72 + kk + quad * 8];
      const shortx8 b0 = *(const shortx8*)&Cb[(0  + m) * 72 + kk + quad * 8];
      acc0 = __builtin_amdgcn_mfma_f32_16x16x32_bf16(a, b0, acc0, 0, 0, 0);
      const shortx8 b1 = *(const shortx8*)&Cb[(16 + m) * 72 + kk + quad * 8];
      acc1 = __builtin_amdgcn_mfma_f32_16x16x32_bf16(a, b1, acc1, 0, 0, 0);
      const shortx8 b2 = *(const shortx8*)&Cb[(32 + m) * 72 + kk + quad * 8];
      acc2 = __builtin_amdgcn_mfma_f32_16x16x32_bf16(a, b2, acc2, 0, 0, 0);
      const shortx8 b3 = *(const shortx8*)&Cb[(48 + m) * 72 + kk + quad * 8];
      acc3 = __builtin_amdgcn_mfma_f32_16x16x32_bf16(a, b3, acc3, 0, 0, 0);
    }
  }

  __syncthreads();
#pragma unroll
  for (int r = 0; r < 4; ++r) {
    const int row = w * 16 + quad * 4 + r;
    Lg[row * 68 + 0  + m] = acc0[r];
    Lg[row * 68 + 16 + m] = acc1[r];
    Lg[row * 68 + 32 + m] = acc2[r];
    Lg[row * 68 + 48 + m] = acc3[r];
  }
  __syncthreads();

  if (t < 64) {
    const int r = t;
    float mx = -1e30f;
#pragma unroll
    for (int c4 = 0; c4 < 16; ++c4) {
      const float4 v = *(const float4*)&Lg[r * 68 + c4 * 4];
      mx = fmaxf(mx, fmaxf(fmaxf(v.x, v.y), fmaxf(v.z, v.w)));
    }
    float sum = 0.f;
#pragma unroll
    for (int c4 = 0; c4 < 16; ++c4) {
      const float4 v = *(const float4*)&Lg[r * 68 + c4 * 4];
      sum += __expf(v.x - mx) + __expf(v.y - mx) + __expf(v.z - mx) + __expf(v.w - mx);
    }
    const int lab = seg[i0 + r];
    const float ce = mx + __logf(sum) - Lg[r * 68 + lab];
    const float4* sp = (const float4*)&sim[(size_t)(i0 + r) * 16];
    const float4 w0 = sp[0], w1 = sp[1], w2 = sp[2], w3 = sp[3];
    const float wgt = (w0.x + w0.y + w0.z + w0.w + w1.x + w1.y + w1.z + w1.w +
                       w2.x + w2.y + w2.z + w2.w + w3.x + w3.y + w3.z + w3.w) * (1.0f / 16.0f);
    float v = ce * wgt * SCALE;
#pragma unroll
    for (int off = 32; off > 0; off >>= 1) v += __shfl_down(v, off, 64);
    if (t == 0) atomicAdd(out, v);
  }
}

extern "C" void kernel_launch(void* const* d_in, const int* in_sizes, int n_in,
                              void* d_out, int out_size, void* d_ws, size_t ws_size,
                              hipStream_t stream) {
  const float* S1  = (const float*)d_in[0];
  const float* S2  = (const float*)d_in[1];
  const int*   seg = (const int*)d_in[2];
  const float* sim = (const float*)d_in[3];
  char* ws = (char*)d_ws;
  float* sums   = (float*)(ws + OFF_SUMS);
  int*   hist   = (int*)(ws + OFF_HIST);
  int*   cursor = (int*)(ws + OFF_CURSOR);
  int*   idx    = (int*)(ws + OFF_IDX);
  unsigned short* centbf = (unsigned short*)(ws + OFF_CENTBF);
  float* out = (float*)d_out;

  hipMemsetAsync(ws + OFF_HIST, 0, 512, stream);   // hist + cursor only
  hipMemsetAsync(d_out, 0, sizeof(float), stream);

  k_hist<<<64, 256, 0, stream>>>(seg, hist);
  k_scatter2<<<32, 1024, 0, stream>>>(seg, hist, cursor, idx);
  k_sumsC<<<512, 256, 0, stream>>>(S1, idx, hist, sums);
  k_cent<<<128, 256, 0, stream>>>(sums, hist, centbf);
  k_loss<<<2048, 256, 0, stream>>>(S1, S2, seg, sim, centbf, out);
}